// Round 2
// baseline (195.943 us; speedup 1.0000x reference)
//
#include <hip/hip_runtime.h>
#include <hip/hip_bf16.h>

#define NNODES 50000
#define DIM    128
#define KNBR   16
#define NPAIRS 100000
#define MBLK   128   // pairs per block in pair_mlp

typedef float          f32x4  __attribute__((ext_vector_type(4)));
typedef __bf16         bf16x8 __attribute__((ext_vector_type(8)));
typedef unsigned short u16x4  __attribute__((ext_vector_type(4)));
typedef unsigned short u16x8  __attribute__((ext_vector_type(8)));

// ---- bf16 helpers (RNE round via bit trick; values are all normal floats) ----
__device__ __forceinline__ unsigned short f2bf(float f) {
    unsigned int u = __builtin_bit_cast(unsigned int, f);
    u = (u + 0x7fffu + ((u >> 16) & 1u)) >> 16;
    return (unsigned short)u;
}
__device__ __forceinline__ float bf2f(unsigned short u) {
    return __builtin_bit_cast(float, (unsigned int)u << 16);
}

#define AS1 __attribute__((address_space(1)))
#define AS3 __attribute__((address_space(3)))
__device__ __forceinline__ void gload_lds16(const void* g, void* l) {
    // dest = wave-uniform LDS base + lane*16 ; source address is per-lane
    __builtin_amdgcn_global_load_lds((AS1 void*)(g), (AS3 void*)(l), 16, 0, 0);
}

// ---------------- K0: W1 [256][128] f32 -> W1t [128][256] bf16 ----------------
__global__ void w1t_kernel(const float* __restrict__ W1, unsigned short* __restrict__ W1t) {
    int g = blockIdx.x * 256 + threadIdx.x;   // coalesced read of W1
    int i = g >> 7;          // k index 0..255
    int d = g & 127;         // col 0..127
    W1t[d * 256 + i] = f2bf(W1[g]);
}

// ---------------- K1: H1 = mean_k E[nbr] ; E fp32 -> H1 bf16 -----------------
// 32 lanes per node (float4 per lane), 8 nodes per 256-thread block.
__global__ void agg1_kernel(const float* __restrict__ E, const int* __restrict__ nbr,
                            unsigned short* __restrict__ H1b) {
    int t = threadIdx.x;
    int node = blockIdx.x * 8 + (t >> 5);
    int c = t & 31;
    const int* nl = nbr + node * KNBR;
    float a0 = 0.f, a1 = 0.f, a2 = 0.f, a3 = 0.f;
#pragma unroll
    for (int k = 0; k < KNBR; ++k) {
        const f32x4 v = *(const f32x4*)(E + (size_t)nl[k] * DIM + c * 4);
        a0 += v[0]; a1 += v[1]; a2 += v[2]; a3 += v[3];
    }
    u16x4 o;
    o[0] = f2bf(a0 * 0.0625f); o[1] = f2bf(a1 * 0.0625f);
    o[2] = f2bf(a2 * 0.0625f); o[3] = f2bf(a3 * 0.0625f);
    *(u16x4*)(H1b + (size_t)node * DIM + c * 4) = o;
}

// ---------------- K2: H2 = mean_k H1[nbr] ; bf16 -> bf16 ---------------------
// 16 lanes per node (16B per lane), 16 nodes per 256-thread block.
__global__ void agg2_kernel(const unsigned short* __restrict__ H1b, const int* __restrict__ nbr,
                            unsigned short* __restrict__ H2b) {
    int t = threadIdx.x;
    int node = blockIdx.x * 16 + (t >> 4);
    int c = t & 15;
    const int* nl = nbr + node * KNBR;
    float a[8] = {0.f,0.f,0.f,0.f,0.f,0.f,0.f,0.f};
#pragma unroll
    for (int k = 0; k < KNBR; ++k) {
        const u16x8 v = *(const u16x8*)(H1b + (size_t)nl[k] * DIM + c * 8);
#pragma unroll
        for (int j = 0; j < 8; ++j) a[j] += bf2f(v[j]);
    }
    u16x8 o;
#pragma unroll
    for (int j = 0; j < 8; ++j) o[j] = f2bf(a[j] * 0.0625f);
    *(u16x8*)(H2b + (size_t)node * DIM + c * 8) = o;
}

// ---------------- K3: fused pair gather + MLP + loss -------------------------
// Per block: 128 pairs. X tile As[128][256] bf16 (swizzled), W1t tile Bs[128][256]
// bf16 (swizzled, col-major i.e. W1^T so A/B frags are k-contiguous 16B reads).
// 4 waves: wave w owns output cols [w*32, w*32+32), all 128 rows.
// Swizzle: LDS byte-in-row ^= ((row&7)<<4); staged via linear LDS dest +
// pre-swizzled per-lane GLOBAL source (global_load_lds rule).
__global__ __launch_bounds__(256, 1) void pair_mlp_kernel(
    const int* __restrict__ pairs, const int* __restrict__ labels,
    const unsigned short* __restrict__ H2b, const unsigned short* __restrict__ W1t,
    const float* __restrict__ b1, const float* __restrict__ W2,
    const float* __restrict__ b2, float* __restrict__ out) {
    __shared__ unsigned short As[MBLK * 256];   // 64 KiB
    __shared__ unsigned short Bs[128 * 256];    // 64 KiB
    __shared__ float LP[4][MBLK][2];            // per-wave logit partials
    __shared__ float wred[4];

    const int t    = threadIdx.x;
    const int wave = t >> 6;
    const int lane = t & 63;
    const int base = blockIdx.x * MBLK;

    const int lq = (lane & 31) * 16;   // byte within 512B LDS row, [0,496]
    const int lr = lane >> 5;          // which of the 2 rows this instr covers

    // ---- stage B: W1t rows d (512B each), 2 rows per global_load_lds ----
#pragma unroll
    for (int i = 0; i < 16; ++i) {
        int d0 = wave * 32 + i * 2;
        int d  = d0 + lr;
        int b  = lq ^ ((d & 7) << 4);  // pre-swizzled source byte
        gload_lds16((const char*)W1t + d * 512 + b, (char*)Bs + d0 * 512);
    }
    // ---- stage A: row m = pair, bytes [0,256)=src node, [256,512)=dst node ----
#pragma unroll
    for (int i = 0; i < 16; ++i) {
        int m0 = wave * 32 + i * 2;
        int m  = m0 + lr;
        int b  = lq ^ ((m & 7) << 4);  // XOR only touches bits 4-6: stays in half
        int half = lq >> 8;            // 0: src endpoint, 1: dst endpoint
        int pm = base + m; if (pm >= NPAIRS) pm = NPAIRS - 1;
        int node = pairs[pm * 2 + half];
        gload_lds16((const char*)H2b + (size_t)node * 256 + (b & 255),
                    (char*)As + m0 * 512);
    }
    __syncthreads();   // compiler emits vmcnt(0) drain before barrier

    // ---- MFMA: C[128][32] per wave, 16x16x32 bf16, K=256 in 8 steps ----
    const int lg = lane >> 4;   // k-group 0..3
    const int ll = lane & 15;   // row (A) / col (B) within fragment
    f32x4 acc[8][2];
    {
        f32x4 z = {0.f, 0.f, 0.f, 0.f};
#pragma unroll
        for (int i = 0; i < 8; ++i) { acc[i][0] = z; acc[i][1] = z; }
    }
    const int col0 = wave * 32 + ll;
    const int col1 = col0 + 16;
#pragma unroll
    for (int ks = 0; ks < 8; ++ks) {
        const int kb = ks * 64 + lg * 16;   // byte offset of this lane's k0 (=k0*2)
        bf16x8 bf0 = *(const bf16x8*)((const char*)Bs + col0 * 512 + (kb ^ ((col0 & 7) << 4)));
        bf16x8 bf1 = *(const bf16x8*)((const char*)Bs + col1 * 512 + (kb ^ ((col1 & 7) << 4)));
#pragma unroll
        for (int mf = 0; mf < 8; ++mf) {
            int row = mf * 16 + ll;
            bf16x8 af = *(const bf16x8*)((const char*)As + row * 512 + (kb ^ ((row & 7) << 4)));
            acc[mf][0] = __builtin_amdgcn_mfma_f32_16x16x32_bf16(af, bf0, acc[mf][0], 0, 0, 0);
            acc[mf][1] = __builtin_amdgcn_mfma_f32_16x16x32_bf16(af, bf1, acc[mf][1], 0, 0, 0);
        }
    }

    // ---- epilogue: +b1, ReLU, @W2 partials, 16-lane reduce -> LP ----
    {
        const float b1v0 = b1[col0], b1v1 = b1[col1];
        const float w2a0 = W2[col0 * 2], w2b0 = W2[col0 * 2 + 1];
        const float w2a1 = W2[col1 * 2], w2b1 = W2[col1 * 2 + 1];
#pragma unroll
        for (int mf = 0; mf < 8; ++mf) {
            float p0[4], p1[4];
#pragma unroll
            for (int r = 0; r < 4; ++r) {
                float h0 = fmaxf(acc[mf][0][r] + b1v0, 0.f);
                float h1 = fmaxf(acc[mf][1][r] + b1v1, 0.f);
                p0[r] = h0 * w2a0 + h1 * w2a1;
                p1[r] = h0 * w2b0 + h1 * w2b1;
            }
#pragma unroll
            for (int s = 1; s < 16; s <<= 1) {
#pragma unroll
                for (int r = 0; r < 4; ++r) {
                    p0[r] += __shfl_xor(p0[r], s, 16);
                    p1[r] += __shfl_xor(p1[r], s, 16);
                }
            }
            if (ll == 0) {
                int rb = mf * 16 + lg * 4;   // C/D layout: row=(lane>>4)*4+reg
#pragma unroll
                for (int r = 0; r < 4; ++r) {
                    LP[wave][rb + r][0] = p0[r];
                    LP[wave][rb + r][1] = p1[r];
                }
            }
        }
    }
    __syncthreads();

    // ---- loss: logits -> softmax -> log_softmax(softmax) -> CE ----
    float myloss = 0.f;
    if (t < MBLK) {
        int pm = base + t;
        if (pm < NPAIRS) {
            float l0 = b2[0] + LP[0][t][0] + LP[1][t][0] + LP[2][t][0] + LP[3][t][0];
            float l1 = b2[1] + LP[0][t][1] + LP[1][t][1] + LP[2][t][1] + LP[3][t][1];
            float mx = fmaxf(l0, l1);
            float e0 = __expf(l0 - mx), e1 = __expf(l1 - mx);
            float inv = 1.f / (e0 + e1);
            float q0 = e0 * inv, q1 = e1 * inv;
            float lse2 = __logf(__expf(q0) + __expf(q1));   // logsumexp over probs
            myloss = lse2 - (labels[pm] ? q1 : q0);
        }
    }
#pragma unroll
    for (int s = 1; s < 64; s <<= 1) myloss += __shfl_xor(myloss, s, 64);
    if (lane == 0) wred[wave] = myloss;
    __syncthreads();
    if (t == 0)
        atomicAdd(out, (wred[0] + wred[1] + wred[2] + wred[3]) * (1.0f / (float)NPAIRS));
}

extern "C" void kernel_launch(void* const* d_in, const int* in_sizes, int n_in,
                              void* d_out, int out_size, void* d_ws, size_t ws_size,
                              hipStream_t stream) {
    const int*   pairs  = (const int*)d_in[0];
    const int*   labels = (const int*)d_in[1];
    const int*   nbr    = (const int*)d_in[2];
    const float* E      = (const float*)d_in[3];
    const float* W1     = (const float*)d_in[4];
    const float* b1     = (const float*)d_in[5];
    const float* W2     = (const float*)d_in[6];
    const float* b2     = (const float*)d_in[7];
    float* out = (float*)d_out;

    // workspace layout (all 256B-aligned): W1t bf16 | H1 bf16 | H2 bf16
    char* ws = (char*)d_ws;
    unsigned short* W1t = (unsigned short*)(ws);
    unsigned short* H1b = (unsigned short*)(ws + 65536);
    unsigned short* H2b = (unsigned short*)(ws + 65536 + (size_t)NNODES * DIM * 2);

    hipMemsetAsync(out, 0, sizeof(float), stream);

    w1t_kernel<<<dim3((256 * 128) / 256), dim3(256), 0, stream>>>(W1, W1t);
    agg1_kernel<<<dim3(NNODES / 8), dim3(256), 0, stream>>>(E, nbr, H1b);
    agg2_kernel<<<dim3(NNODES / 16), dim3(256), 0, stream>>>(H1b, nbr, H2b);
    pair_mlp_kernel<<<dim3((NPAIRS + MBLK - 1) / MBLK), dim3(256), 0, stream>>>(
        pairs, labels, H2b, W1t, b1, W2, b2, out);
}

// Round 4
// 149.577 us; speedup vs baseline: 1.3100x; 1.3100x over previous
//
#include <hip/hip_runtime.h>
#include <hip/hip_bf16.h>

#define NNODES 50000
#define DIM    128
#define KNBR   16
#define NPAIRS 100000
#define MBLK   128   // pairs per block in pair_mlp

typedef float          f32x4  __attribute__((ext_vector_type(4)));
typedef float          f32x2  __attribute__((ext_vector_type(2)));
typedef __bf16         bf16x8 __attribute__((ext_vector_type(8)));
typedef unsigned short u16x8  __attribute__((ext_vector_type(8)));
typedef unsigned int   u32x2  __attribute__((ext_vector_type(2)));

// ---- bf16 helpers (RNE round via bit trick; values are all normal floats) ----
__device__ __forceinline__ unsigned short f2bf(float f) {
    unsigned int u = __builtin_bit_cast(unsigned int, f);
    u = (u + 0x7fffu + ((u >> 16) & 1u)) >> 16;
    return (unsigned short)u;
}

// ---- fp8 e4m3 codecs: HW cvt ops (gfx950: OCP e4m3fn) with SW fallback ------
// The builtins require the hi/word-select to be a LITERAL constant -> template.
#if __has_builtin(__builtin_amdgcn_cvt_pk_f32_fp8) && __has_builtin(__builtin_amdgcn_cvt_pk_fp8_f32)
template <bool HI>
__device__ __forceinline__ f32x2 fp8x2_dec(unsigned int w) {
    return __builtin_amdgcn_cvt_pk_f32_fp8((int)w, HI);
}
template <bool HI>
__device__ __forceinline__ unsigned int fp8x2_enc(float a, float b, unsigned int old) {
    return (unsigned int)__builtin_amdgcn_cvt_pk_fp8_f32(a, b, (int)old, HI);
}
#else
__device__ __forceinline__ float e4m3_dec1(unsigned int b) {
    unsigned int s = (b & 0x80u) << 24;
    unsigned int em = b & 0x7fu;
    float mag = (em >= 8u)
        ? __builtin_bit_cast(float, (((em >> 3) + 120u) << 23) | ((em & 7u) << 20))
        : (float)em * 0.001953125f;   // denormal: em * 2^-9
    return __builtin_bit_cast(float, __builtin_bit_cast(unsigned int, mag) | s);
}
template <bool HI>
__device__ __forceinline__ f32x2 fp8x2_dec(unsigned int w) {
    unsigned int v = HI ? (w >> 16) : w;
    f32x2 r; r[0] = e4m3_dec1(v & 0xffu); r[1] = e4m3_dec1((v >> 8) & 0xffu);
    return r;
}
__device__ __forceinline__ unsigned int e4m3_enc1(float f) {
    unsigned int s = (__builtin_bit_cast(unsigned int, f) >> 24) & 0x80u;
    float af = fminf(fabsf(f), 448.0f);
    unsigned int u = __builtin_bit_cast(unsigned int, af);
    int e = (int)(u >> 23) - 127;
    if (e < -9) return s;
    if (e < -6) {
        int q = (int)rintf(af * 512.0f);
        return s | (unsigned int)q;
    }
    unsigned int mant = u & 0x7fffffu;
    unsigned int r = (mant + 0x7ffffu + ((mant >> 20) & 1u)) >> 20;
    unsigned int out = (((unsigned int)(e + 7)) << 3) + r;
    if (out > 0x7eu) out = 0x7eu;
    return s | out;
}
template <bool HI>
__device__ __forceinline__ unsigned int fp8x2_enc(float a, float b, unsigned int old) {
    unsigned int p = e4m3_enc1(a) | (e4m3_enc1(b) << 8);
    return HI ? ((old & 0x0000ffffu) | (p << 16)) : ((old & 0xffff0000u) | p);
}
#endif

#define AS1 __attribute__((address_space(1)))
#define AS3 __attribute__((address_space(3)))
__device__ __forceinline__ void gload_lds16(const void* g, void* l) {
    __builtin_amdgcn_global_load_lds((AS1 void*)(g), (AS3 void*)(l), 16, 0, 0);
}

// ---------------- K0: W1 [256][128] f32 -> W1t [128][256] bf16 ----------------
__global__ void w1t_kernel(const float* __restrict__ W1, unsigned short* __restrict__ W1t) {
    int g = blockIdx.x * 256 + threadIdx.x;
    int i = g >> 7;
    int d = g & 127;
    W1t[d * 256 + i] = f2bf(W1[g]);
}

// ---------------- K0b: E f32 -> E8 fp8 (sequential, 8 elems/thread) ----------
__global__ void e2f8_kernel(const float* __restrict__ E, unsigned int* __restrict__ E8) {
    int g = blockIdx.x * 256 + threadIdx.x;
    const f32x4 v0 = *(const f32x4*)(E + (size_t)g * 8);
    const f32x4 v1 = *(const f32x4*)(E + (size_t)g * 8 + 4);
    unsigned int w0 = 0, w1 = 0;
    w0 = fp8x2_enc<false>(v0[0], v0[1], w0);
    w0 = fp8x2_enc<true >(v0[2], v0[3], w0);
    w1 = fp8x2_enc<false>(v1[0], v1[1], w1);
    w1 = fp8x2_enc<true >(v1[2], v1[3], w1);
    u32x2 o; o[0] = w0; o[1] = w1;
    *(u32x2*)(E8 + (size_t)g * 2) = o;
}

// ---------------- K1: H1 = mean_k E8[nbr] ; fp8 -> fp8 -----------------------
// 16 lanes per node (8B = 8 fp8 per lane), 16 nodes per 256-thread block.
__global__ void agg1_kernel(const unsigned char* __restrict__ E8, const int* __restrict__ nbr,
                            unsigned char* __restrict__ H1f8) {
    int t = threadIdx.x;
    int node = blockIdx.x * 16 + (t >> 4);
    int c = t & 15;
    const int* nl = nbr + node * KNBR;
    float a[8] = {0.f,0.f,0.f,0.f,0.f,0.f,0.f,0.f};
#pragma unroll
    for (int k = 0; k < KNBR; ++k) {
        const u32x2 w = *(const u32x2*)(E8 + (size_t)nl[k] * 128 + c * 8);
        f32x2 f;
        f = fp8x2_dec<false>(w[0]); a[0] += f[0]; a[1] += f[1];
        f = fp8x2_dec<true >(w[0]); a[2] += f[0]; a[3] += f[1];
        f = fp8x2_dec<false>(w[1]); a[4] += f[0]; a[5] += f[1];
        f = fp8x2_dec<true >(w[1]); a[6] += f[0]; a[7] += f[1];
    }
    unsigned int w0 = 0, w1 = 0;
    w0 = fp8x2_enc<false>(a[0] * 0.0625f, a[1] * 0.0625f, w0);
    w0 = fp8x2_enc<true >(a[2] * 0.0625f, a[3] * 0.0625f, w0);
    w1 = fp8x2_enc<false>(a[4] * 0.0625f, a[5] * 0.0625f, w1);
    w1 = fp8x2_enc<true >(a[6] * 0.0625f, a[7] * 0.0625f, w1);
    u32x2 o; o[0] = w0; o[1] = w1;
    *(u32x2*)(H1f8 + (size_t)node * 128 + c * 8) = o;
}

// ---------------- K2: H2 = mean_k H1f8[nbr] ; fp8 -> bf16 --------------------
__global__ void agg2_kernel(const unsigned char* __restrict__ H1f8, const int* __restrict__ nbr,
                            unsigned short* __restrict__ H2b) {
    int t = threadIdx.x;
    int node = blockIdx.x * 16 + (t >> 4);
    int c = t & 15;
    const int* nl = nbr + node * KNBR;
    float a[8] = {0.f,0.f,0.f,0.f,0.f,0.f,0.f,0.f};
#pragma unroll
    for (int k = 0; k < KNBR; ++k) {
        const u32x2 w = *(const u32x2*)(H1f8 + (size_t)nl[k] * 128 + c * 8);
        f32x2 f;
        f = fp8x2_dec<false>(w[0]); a[0] += f[0]; a[1] += f[1];
        f = fp8x2_dec<true >(w[0]); a[2] += f[0]; a[3] += f[1];
        f = fp8x2_dec<false>(w[1]); a[4] += f[0]; a[5] += f[1];
        f = fp8x2_dec<true >(w[1]); a[6] += f[0]; a[7] += f[1];
    }
    u16x8 o;
#pragma unroll
    for (int j = 0; j < 8; ++j) o[j] = f2bf(a[j] * 0.0625f);
    *(u16x8*)(H2b + (size_t)node * DIM + c * 8) = o;
}

// ---------------- K3: fused pair gather + MLP + loss (unchanged) -------------
__global__ __launch_bounds__(256, 1) void pair_mlp_kernel(
    const int* __restrict__ pairs, const int* __restrict__ labels,
    const unsigned short* __restrict__ H2b, const unsigned short* __restrict__ W1t,
    const float* __restrict__ b1, const float* __restrict__ W2,
    const float* __restrict__ b2, float* __restrict__ out) {
    __shared__ unsigned short As[MBLK * 256];   // 64 KiB
    __shared__ unsigned short Bs[128 * 256];    // 64 KiB
    __shared__ float LP[4][MBLK][2];
    __shared__ float wred[4];

    const int t    = threadIdx.x;
    const int wave = t >> 6;
    const int lane = t & 63;
    const int base = blockIdx.x * MBLK;

    const int lq = (lane & 31) * 16;
    const int lr = lane >> 5;

#pragma unroll
    for (int i = 0; i < 16; ++i) {
        int d0 = wave * 32 + i * 2;
        int d  = d0 + lr;
        int b  = lq ^ ((d & 7) << 4);
        gload_lds16((const char*)W1t + d * 512 + b, (char*)Bs + d0 * 512);
    }
#pragma unroll
    for (int i = 0; i < 16; ++i) {
        int m0 = wave * 32 + i * 2;
        int m  = m0 + lr;
        int b  = lq ^ ((m & 7) << 4);
        int half = lq >> 8;
        int pm = base + m; if (pm >= NPAIRS) pm = NPAIRS - 1;
        int node = pairs[pm * 2 + half];
        gload_lds16((const char*)H2b + (size_t)node * 256 + (b & 255),
                    (char*)As + m0 * 512);
    }
    __syncthreads();

    const int lg = lane >> 4;
    const int ll = lane & 15;
    f32x4 acc[8][2];
    {
        f32x4 z = {0.f, 0.f, 0.f, 0.f};
#pragma unroll
        for (int i = 0; i < 8; ++i) { acc[i][0] = z; acc[i][1] = z; }
    }
    const int col0 = wave * 32 + ll;
    const int col1 = col0 + 16;
#pragma unroll
    for (int ks = 0; ks < 8; ++ks) {
        const int kb = ks * 64 + lg * 16;
        bf16x8 bf0 = *(const bf16x8*)((const char*)Bs + col0 * 512 + (kb ^ ((col0 & 7) << 4)));
        bf16x8 bf1 = *(const bf16x8*)((const char*)Bs + col1 * 512 + (kb ^ ((col1 & 7) << 4)));
#pragma unroll
        for (int mf = 0; mf < 8; ++mf) {
            int row = mf * 16 + ll;
            bf16x8 af = *(const bf16x8*)((const char*)As + row * 512 + (kb ^ ((row & 7) << 4)));
            acc[mf][0] = __builtin_amdgcn_mfma_f32_16x16x32_bf16(af, bf0, acc[mf][0], 0, 0, 0);
            acc[mf][1] = __builtin_amdgcn_mfma_f32_16x16x32_bf16(af, bf1, acc[mf][1], 0, 0, 0);
        }
    }

    {
        const float b1v0 = b1[col0], b1v1 = b1[col1];
        const float w2a0 = W2[col0 * 2], w2b0 = W2[col0 * 2 + 1];
        const float w2a1 = W2[col1 * 2], w2b1 = W2[col1 * 2 + 1];
#pragma unroll
        for (int mf = 0; mf < 8; ++mf) {
            float p0[4], p1[4];
#pragma unroll
            for (int r = 0; r < 4; ++r) {
                float h0 = fmaxf(acc[mf][0][r] + b1v0, 0.f);
                float h1 = fmaxf(acc[mf][1][r] + b1v1, 0.f);
                p0[r] = h0 * w2a0 + h1 * w2a1;
                p1[r] = h0 * w2b0 + h1 * w2b1;
            }
#pragma unroll
            for (int s = 1; s < 16; s <<= 1) {
#pragma unroll
                for (int r = 0; r < 4; ++r) {
                    p0[r] += __shfl_xor(p0[r], s, 16);
                    p1[r] += __shfl_xor(p1[r], s, 16);
                }
            }
            if (ll == 0) {
                int rb = mf * 16 + lg * 4;
#pragma unroll
                for (int r = 0; r < 4; ++r) {
                    LP[wave][rb + r][0] = p0[r];
                    LP[wave][rb + r][1] = p1[r];
                }
            }
        }
    }
    __syncthreads();

    float myloss = 0.f;
    if (t < MBLK) {
        int pm = base + t;
        if (pm < NPAIRS) {
            float l0 = b2[0] + LP[0][t][0] + LP[1][t][0] + LP[2][t][0] + LP[3][t][0];
            float l1 = b2[1] + LP[0][t][1] + LP[1][t][1] + LP[2][t][1] + LP[3][t][1];
            float mx = fmaxf(l0, l1);
            float e0 = __expf(l0 - mx), e1 = __expf(l1 - mx);
            float inv = 1.f / (e0 + e1);
            float q0 = e0 * inv, q1 = e1 * inv;
            float lse2 = __logf(__expf(q0) + __expf(q1));
            myloss = lse2 - (labels[pm] ? q1 : q0);
        }
    }
#pragma unroll
    for (int s = 1; s < 64; s <<= 1) myloss += __shfl_xor(myloss, s, 64);
    if (lane == 0) wred[wave] = myloss;
    __syncthreads();
    if (t == 0)
        atomicAdd(out, (wred[0] + wred[1] + wred[2] + wred[3]) * (1.0f / (float)NPAIRS));
}

extern "C" void kernel_launch(void* const* d_in, const int* in_sizes, int n_in,
                              void* d_out, int out_size, void* d_ws, size_t ws_size,
                              hipStream_t stream) {
    const int*   pairs  = (const int*)d_in[0];
    const int*   labels = (const int*)d_in[1];
    const int*   nbr    = (const int*)d_in[2];
    const float* E      = (const float*)d_in[3];
    const float* W1     = (const float*)d_in[4];
    const float* b1     = (const float*)d_in[5];
    const float* W2     = (const float*)d_in[6];
    const float* b2     = (const float*)d_in[7];
    float* out = (float*)d_out;

    // workspace: W1t bf16 (64KB) | E8 fp8 (6.4MB) | H1f8 fp8 (6.4MB) | H2b bf16 (12.8MB)
    char* ws = (char*)d_ws;
    unsigned short* W1t  = (unsigned short*)(ws);
    unsigned char*  E8   = (unsigned char*)(ws + 65536);
    unsigned char*  H1f8 = E8 + (size_t)NNODES * DIM;
    unsigned short* H2b  = (unsigned short*)(H1f8 + (size_t)NNODES * DIM);

    (void)hipMemsetAsync(out, 0, sizeof(float), stream);

    w1t_kernel<<<dim3(128), dim3(256), 0, stream>>>(W1, W1t);
    e2f8_kernel<<<dim3((NNODES * DIM) / (256 * 8)), dim3(256), 0, stream>>>(E, (unsigned int*)E8);
    agg1_kernel<<<dim3(NNODES / 16), dim3(256), 0, stream>>>(E8, nbr, H1f8);
    agg2_kernel<<<dim3(NNODES / 16), dim3(256), 0, stream>>>(H1f8, nbr, H2b);
    pair_mlp_kernel<<<dim3((NPAIRS + MBLK - 1) / MBLK), dim3(256), 0, stream>>>(
        pairs, labels, H2b, W1t, b1, W2, b2, out);
}

// Round 5
// 144.632 us; speedup vs baseline: 1.3548x; 1.0342x over previous
//
#include <hip/hip_runtime.h>
#include <hip/hip_bf16.h>

#define NNODES 50000
#define DIM    128
#define KNBR   16
#define NPAIRS 100000
#define MBLK   128   // pairs per block in pair_mlp

typedef float          f32x4  __attribute__((ext_vector_type(4)));
typedef float          f32x2  __attribute__((ext_vector_type(2)));
typedef __bf16         bf16x8 __attribute__((ext_vector_type(8)));
typedef unsigned short u16x8  __attribute__((ext_vector_type(8)));
typedef unsigned int   u32x2  __attribute__((ext_vector_type(2)));

// ---- bf16 helpers (RNE round via bit trick; values are all normal floats) ----
__device__ __forceinline__ unsigned short f2bf(float f) {
    unsigned int u = __builtin_bit_cast(unsigned int, f);
    u = (u + 0x7fffu + ((u >> 16) & 1u)) >> 16;
    return (unsigned short)u;
}

// ---- fp8 e4m3 codecs: HW cvt ops (selector must be a literal -> template) ----
#if __has_builtin(__builtin_amdgcn_cvt_pk_f32_fp8) && __has_builtin(__builtin_amdgcn_cvt_pk_fp8_f32)
template <bool HI>
__device__ __forceinline__ f32x2 fp8x2_dec(unsigned int w) {
    return __builtin_amdgcn_cvt_pk_f32_fp8((int)w, HI);
}
template <bool HI>
__device__ __forceinline__ unsigned int fp8x2_enc(float a, float b, unsigned int old) {
    return (unsigned int)__builtin_amdgcn_cvt_pk_fp8_f32(a, b, (int)old, HI);
}
#else
__device__ __forceinline__ float e4m3_dec1(unsigned int b) {
    unsigned int s = (b & 0x80u) << 24;
    unsigned int em = b & 0x7fu;
    float mag = (em >= 8u)
        ? __builtin_bit_cast(float, (((em >> 3) + 120u) << 23) | ((em & 7u) << 20))
        : (float)em * 0.001953125f;
    return __builtin_bit_cast(float, __builtin_bit_cast(unsigned int, mag) | s);
}
template <bool HI>
__device__ __forceinline__ f32x2 fp8x2_dec(unsigned int w) {
    unsigned int v = HI ? (w >> 16) : w;
    f32x2 r; r[0] = e4m3_dec1(v & 0xffu); r[1] = e4m3_dec1((v >> 8) & 0xffu);
    return r;
}
__device__ __forceinline__ unsigned int e4m3_enc1(float f) {
    unsigned int s = (__builtin_bit_cast(unsigned int, f) >> 24) & 0x80u;
    float af = fminf(fabsf(f), 448.0f);
    unsigned int u = __builtin_bit_cast(unsigned int, af);
    int e = (int)(u >> 23) - 127;
    if (e < -9) return s;
    if (e < -6) {
        int q = (int)rintf(af * 512.0f);
        return s | (unsigned int)q;
    }
    unsigned int mant = u & 0x7fffffu;
    unsigned int r = (mant + 0x7ffffu + ((mant >> 20) & 1u)) >> 20;
    unsigned int out = (((unsigned int)(e + 7)) << 3) + r;
    if (out > 0x7eu) out = 0x7eu;
    return s | out;
}
template <bool HI>
__device__ __forceinline__ unsigned int fp8x2_enc(float a, float b, unsigned int old) {
    unsigned int p = e4m3_enc1(a) | (e4m3_enc1(b) << 8);
    return HI ? ((old & 0x0000ffffu) | (p << 16)) : ((old & 0xffff0000u) | p);
}
#endif

#define AS1 __attribute__((address_space(1)))
#define AS3 __attribute__((address_space(3)))
__device__ __forceinline__ void gload_lds16(const void* g, void* l) {
    __builtin_amdgcn_global_load_lds((AS1 void*)(g), (AS3 void*)(l), 16, 0, 0);
}

// ---------------- K0: W1 [256][128] f32 -> W1t [128][256] bf16 ----------------
__global__ void w1t_kernel(const float* __restrict__ W1, unsigned short* __restrict__ W1t) {
    int g = blockIdx.x * 256 + threadIdx.x;
    int i = g >> 7;
    int d = g & 127;
    W1t[d * 256 + i] = f2bf(W1[g]);
}

// ---------------- K0b: E f32 -> E8 fp8 (sequential, 8 elems/thread) ----------
__global__ void e2f8_kernel(const float* __restrict__ E, unsigned int* __restrict__ E8) {
    int g = blockIdx.x * 256 + threadIdx.x;
    const f32x4 v0 = *(const f32x4*)(E + (size_t)g * 8);
    const f32x4 v1 = *(const f32x4*)(E + (size_t)g * 8 + 4);
    unsigned int w0 = 0, w1 = 0;
    w0 = fp8x2_enc<false>(v0[0], v0[1], w0);
    w0 = fp8x2_enc<true >(v0[2], v0[3], w0);
    w1 = fp8x2_enc<false>(v1[0], v1[1], w1);
    w1 = fp8x2_enc<true >(v1[2], v1[3], w1);
    u32x2 o; o[0] = w0; o[1] = w1;
    *(u32x2*)(E8 + (size_t)g * 2) = o;
}

// ---------------- K1: H1 = mean_k E8[nbr] ; fp8 -> fp8 -----------------------
__global__ void agg1_kernel(const unsigned char* __restrict__ E8, const int* __restrict__ nbr,
                            unsigned char* __restrict__ H1f8) {
    int t = threadIdx.x;
    int node = blockIdx.x * 16 + (t >> 4);
    int c = t & 15;
    const int* nl = nbr + node * KNBR;
    float a[8] = {0.f,0.f,0.f,0.f,0.f,0.f,0.f,0.f};
#pragma unroll
    for (int k = 0; k < KNBR; ++k) {
        const u32x2 w = *(const u32x2*)(E8 + (size_t)nl[k] * 128 + c * 8);
        f32x2 f;
        f = fp8x2_dec<false>(w[0]); a[0] += f[0]; a[1] += f[1];
        f = fp8x2_dec<true >(w[0]); a[2] += f[0]; a[3] += f[1];
        f = fp8x2_dec<false>(w[1]); a[4] += f[0]; a[5] += f[1];
        f = fp8x2_dec<true >(w[1]); a[6] += f[0]; a[7] += f[1];
    }
    unsigned int w0 = 0, w1 = 0;
    w0 = fp8x2_enc<false>(a[0] * 0.0625f, a[1] * 0.0625f, w0);
    w0 = fp8x2_enc<true >(a[2] * 0.0625f, a[3] * 0.0625f, w0);
    w1 = fp8x2_enc<false>(a[4] * 0.0625f, a[5] * 0.0625f, w1);
    w1 = fp8x2_enc<true >(a[6] * 0.0625f, a[7] * 0.0625f, w1);
    u32x2 o; o[0] = w0; o[1] = w1;
    *(u32x2*)(H1f8 + (size_t)node * 128 + c * 8) = o;
}

// ---------------- K2: H2 = mean_k H1f8[nbr] ; fp8 -> bf16 --------------------
__global__ void agg2_kernel(const unsigned char* __restrict__ H1f8, const int* __restrict__ nbr,
                            unsigned short* __restrict__ H2b) {
    int t = threadIdx.x;
    int node = blockIdx.x * 16 + (t >> 4);
    int c = t & 15;
    const int* nl = nbr + node * KNBR;
    float a[8] = {0.f,0.f,0.f,0.f,0.f,0.f,0.f,0.f};
#pragma unroll
    for (int k = 0; k < KNBR; ++k) {
        const u32x2 w = *(const u32x2*)(H1f8 + (size_t)nl[k] * 128 + c * 8);
        f32x2 f;
        f = fp8x2_dec<false>(w[0]); a[0] += f[0]; a[1] += f[1];
        f = fp8x2_dec<true >(w[0]); a[2] += f[0]; a[3] += f[1];
        f = fp8x2_dec<false>(w[1]); a[4] += f[0]; a[5] += f[1];
        f = fp8x2_dec<true >(w[1]); a[6] += f[0]; a[7] += f[1];
    }
    u16x8 o;
#pragma unroll
    for (int j = 0; j < 8; ++j) o[j] = f2bf(a[j] * 0.0625f);
    *(u16x8*)(H2b + (size_t)node * DIM + c * 8) = o;
}

// ---------------- K3: fused pair gather + MLP + loss -------------------------
// Round-5 change: W1t fragments live in REGISTERS (identical across blocks,
// L2-hot, 64 VGPR/lane) instead of a 64 KiB LDS tile. LDS drops 132->68 KiB
// -> 2 blocks/CU, doubling occupancy so block N+1's compute hides block N's
// gather drain. A-tile staging/swizzle unchanged.
__global__ __launch_bounds__(256, 2) void pair_mlp_kernel(
    const int* __restrict__ pairs, const int* __restrict__ labels,
    const unsigned short* __restrict__ H2b, const unsigned short* __restrict__ W1t,
    const float* __restrict__ b1, const float* __restrict__ W2,
    const float* __restrict__ b2, float* __restrict__ out) {
    __shared__ unsigned short As[MBLK * 256];   // 64 KiB
    __shared__ float LP[4][MBLK][2];            // 4 KiB
    __shared__ float wred[4];

    const int t    = threadIdx.x;
    const int wave = t >> 6;
    const int lane = t & 63;
    const int base = blockIdx.x * MBLK;

    const int lq = (lane & 31) * 16;
    const int lr = lane >> 5;

    // ---- stage A (issue FIRST so gathers are in flight during B-reg loads) ----
#pragma unroll
    for (int i = 0; i < 16; ++i) {
        int m0 = wave * 32 + i * 2;
        int m  = m0 + lr;
        int b  = lq ^ ((m & 7) << 4);
        int half = lq >> 8;
        int pm = base + m; if (pm >= NPAIRS) pm = NPAIRS - 1;
        int node = pairs[pm * 2 + half];
        gload_lds16((const char*)H2b + (size_t)node * 256 + (b & 255),
                    (char*)As + m0 * 512);
    }

    // ---- B fragments: global -> registers (no swizzle; same bytes as before) ----
    const int lg = lane >> 4;
    const int ll = lane & 15;
    const int col0 = wave * 32 + ll;
    const int col1 = col0 + 16;
    bf16x8 breg0[8], breg1[8];
#pragma unroll
    for (int ks = 0; ks < 8; ++ks) {
        const int kb = ks * 64 + lg * 16;
        breg0[ks] = *(const bf16x8*)((const char*)W1t + col0 * 512 + kb);
        breg1[ks] = *(const bf16x8*)((const char*)W1t + col1 * 512 + kb);
    }
    __syncthreads();

    // ---- MFMA: C[128][32] per wave, 16x16x32 bf16, K=256 in 8 steps ----
    f32x4 acc[8][2];
    {
        f32x4 z = {0.f, 0.f, 0.f, 0.f};
#pragma unroll
        for (int i = 0; i < 8; ++i) { acc[i][0] = z; acc[i][1] = z; }
    }
#pragma unroll
    for (int ks = 0; ks < 8; ++ks) {
        const int kb = ks * 64 + lg * 16;
#pragma unroll
        for (int mf = 0; mf < 8; ++mf) {
            int row = mf * 16 + ll;
            bf16x8 af = *(const bf16x8*)((const char*)As + row * 512 + (kb ^ ((row & 7) << 4)));
            acc[mf][0] = __builtin_amdgcn_mfma_f32_16x16x32_bf16(af, breg0[ks], acc[mf][0], 0, 0, 0);
            acc[mf][1] = __builtin_amdgcn_mfma_f32_16x16x32_bf16(af, breg1[ks], acc[mf][1], 0, 0, 0);
        }
    }

    // ---- epilogue: +b1, ReLU, @W2 partials, 16-lane reduce -> LP ----
    {
        const float b1v0 = b1[col0], b1v1 = b1[col1];
        const float w2a0 = W2[col0 * 2], w2b0 = W2[col0 * 2 + 1];
        const float w2a1 = W2[col1 * 2], w2b1 = W2[col1 * 2 + 1];
#pragma unroll
        for (int mf = 0; mf < 8; ++mf) {
            float p0[4], p1[4];
#pragma unroll
            for (int r = 0; r < 4; ++r) {
                float h0 = fmaxf(acc[mf][0][r] + b1v0, 0.f);
                float h1 = fmaxf(acc[mf][1][r] + b1v1, 0.f);
                p0[r] = h0 * w2a0 + h1 * w2a1;
                p1[r] = h0 * w2b0 + h1 * w2b1;
            }
#pragma unroll
            for (int s = 1; s < 16; s <<= 1) {
#pragma unroll
                for (int r = 0; r < 4; ++r) {
                    p0[r] += __shfl_xor(p0[r], s, 16);
                    p1[r] += __shfl_xor(p1[r], s, 16);
                }
            }
            if (ll == 0) {
                int rb = mf * 16 + lg * 4;
#pragma unroll
                for (int r = 0; r < 4; ++r) {
                    LP[wave][rb + r][0] = p0[r];
                    LP[wave][rb + r][1] = p1[r];
                }
            }
        }
    }
    __syncthreads();

    float myloss = 0.f;
    if (t < MBLK) {
        int pm = base + t;
        if (pm < NPAIRS) {
            float l0 = b2[0] + LP[0][t][0] + LP[1][t][0] + LP[2][t][0] + LP[3][t][0];
            float l1 = b2[1] + LP[0][t][1] + LP[1][t][1] + LP[2][t][1] + LP[3][t][1];
            float mx = fmaxf(l0, l1);
            float e0 = __expf(l0 - mx), e1 = __expf(l1 - mx);
            float inv = 1.f / (e0 + e1);
            float q0 = e0 * inv, q1 = e1 * inv;
            float lse2 = __logf(__expf(q0) + __expf(q1));
            myloss = lse2 - (labels[pm] ? q1 : q0);
        }
    }
#pragma unroll
    for (int s = 1; s < 64; s <<= 1) myloss += __shfl_xor(myloss, s, 64);
    if (lane == 0) wred[wave] = myloss;
    __syncthreads();
    if (t == 0)
        atomicAdd(out, (wred[0] + wred[1] + wred[2] + wred[3]) * (1.0f / (float)NPAIRS));
}

extern "C" void kernel_launch(void* const* d_in, const int* in_sizes, int n_in,
                              void* d_out, int out_size, void* d_ws, size_t ws_size,
                              hipStream_t stream) {
    const int*   pairs  = (const int*)d_in[0];
    const int*   labels = (const int*)d_in[1];
    const int*   nbr    = (const int*)d_in[2];
    const float* E      = (const float*)d_in[3];
    const float* W1     = (const float*)d_in[4];
    const float* b1     = (const float*)d_in[5];
    const float* W2     = (const float*)d_in[6];
    const float* b2     = (const float*)d_in[7];
    float* out = (float*)d_out;

    // workspace: W1t bf16 (64KB) | E8 fp8 (6.4MB) | H1f8 fp8 (6.4MB) | H2b bf16 (12.8MB)
    char* ws = (char*)d_ws;
    unsigned short* W1t  = (unsigned short*)(ws);
    unsigned char*  E8   = (unsigned char*)(ws + 65536);
    unsigned char*  H1f8 = E8 + (size_t)NNODES * DIM;
    unsigned short* H2b  = (unsigned short*)(H1f8 + (size_t)NNODES * DIM);

    (void)hipMemsetAsync(out, 0, sizeof(float), stream);

    w1t_kernel<<<dim3(128), dim3(256), 0, stream>>>(W1, W1t);
    e2f8_kernel<<<dim3((NNODES * DIM) / (256 * 8)), dim3(256), 0, stream>>>(E, (unsigned int*)E8);
    agg1_kernel<<<dim3(NNODES / 16), dim3(256), 0, stream>>>(E8, nbr, H1f8);
    agg2_kernel<<<dim3(NNODES / 16), dim3(256), 0, stream>>>(H1f8, nbr, H2b);
    pair_mlp_kernel<<<dim3((NPAIRS + MBLK - 1) / MBLK), dim3(256), 0, stream>>>(
        pairs, labels, H2b, W1t, b1, W2, b2, out);
}

// Round 6
// 140.330 us; speedup vs baseline: 1.3963x; 1.0307x over previous
//
#include <hip/hip_runtime.h>
#include <hip/hip_bf16.h>

#define NNODES 50000
#define DIM    128
#define KNBR   16
#define NPAIRS 100000
#define MBLK   64              // pairs per tile in pair_mlp
#define NT     1563            // ceil(NPAIRS / MBLK)
#define GRID_P 512             // persistent blocks (2 per CU)

typedef float          f32x4  __attribute__((ext_vector_type(4)));
typedef float          f32x2  __attribute__((ext_vector_type(2)));
typedef __bf16         bf16x8 __attribute__((ext_vector_type(8)));
typedef unsigned short u16x8  __attribute__((ext_vector_type(8)));
typedef unsigned int   u32x2  __attribute__((ext_vector_type(2)));
typedef unsigned int   u32x4  __attribute__((ext_vector_type(4)));

// ---- bf16 helper (RNE round) ----
__device__ __forceinline__ unsigned short f2bf(float f) {
    unsigned int u = __builtin_bit_cast(unsigned int, f);
    u = (u + 0x7fffu + ((u >> 16) & 1u)) >> 16;
    return (unsigned short)u;
}

// ---- fp8 e4m3 codecs (HW cvt; selector must be literal -> template) ----
#if __has_builtin(__builtin_amdgcn_cvt_pk_f32_fp8) && __has_builtin(__builtin_amdgcn_cvt_pk_fp8_f32)
template <bool HI>
__device__ __forceinline__ f32x2 fp8x2_dec(unsigned int w) {
    return __builtin_amdgcn_cvt_pk_f32_fp8((int)w, HI);
}
template <bool HI>
__device__ __forceinline__ unsigned int fp8x2_enc(float a, float b, unsigned int old) {
    return (unsigned int)__builtin_amdgcn_cvt_pk_fp8_f32(a, b, (int)old, HI);
}
#else
__device__ __forceinline__ float e4m3_dec1(unsigned int b) {
    unsigned int s = (b & 0x80u) << 24;
    unsigned int em = b & 0x7fu;
    float mag = (em >= 8u)
        ? __builtin_bit_cast(float, (((em >> 3) + 120u) << 23) | ((em & 7u) << 20))
        : (float)em * 0.001953125f;
    return __builtin_bit_cast(float, __builtin_bit_cast(unsigned int, mag) | s);
}
template <bool HI>
__device__ __forceinline__ f32x2 fp8x2_dec(unsigned int w) {
    unsigned int v = HI ? (w >> 16) : w;
    f32x2 r; r[0] = e4m3_dec1(v & 0xffu); r[1] = e4m3_dec1((v >> 8) & 0xffu);
    return r;
}
__device__ __forceinline__ unsigned int e4m3_enc1(float f) {
    unsigned int s = (__builtin_bit_cast(unsigned int, f) >> 24) & 0x80u;
    float af = fminf(fabsf(f), 448.0f);
    unsigned int u = __builtin_bit_cast(unsigned int, af);
    int e = (int)(u >> 23) - 127;
    if (e < -9) return s;
    if (e < -6) { int q = (int)rintf(af * 512.0f); return s | (unsigned int)q; }
    unsigned int mant = u & 0x7fffffu;
    unsigned int r = (mant + 0x7ffffu + ((mant >> 20) & 1u)) >> 20;
    unsigned int out = (((unsigned int)(e + 7)) << 3) + r;
    if (out > 0x7eu) out = 0x7eu;
    return s | out;
}
template <bool HI>
__device__ __forceinline__ unsigned int fp8x2_enc(float a, float b, unsigned int old) {
    unsigned int p = e4m3_enc1(a) | (e4m3_enc1(b) << 8);
    return HI ? ((old & 0x0000ffffu) | (p << 16)) : ((old & 0xffff0000u) | p);
}
#endif

#define AS1 __attribute__((address_space(1)))
#define AS3 __attribute__((address_space(3)))
__device__ __forceinline__ void gload_lds16(const void* g, void* l) {
    __builtin_amdgcn_global_load_lds((AS1 void*)(g), (AS3 void*)(l), 16, 0, 0);
}

// ---------------- K0: W1 [256][128] f32 -> W1t [128][256] bf16 ----------------
__global__ void w1t_kernel(const float* __restrict__ W1, unsigned short* __restrict__ W1t) {
    int g = blockIdx.x * 256 + threadIdx.x;
    int i = g >> 7;
    int d = g & 127;
    W1t[d * 256 + i] = f2bf(W1[g]);
}

// ---------------- K0b: E f32 -> E8 fp8 (sequential, 8 elems/thread) ----------
__global__ void e2f8_kernel(const float* __restrict__ E, unsigned int* __restrict__ E8) {
    int g = blockIdx.x * 256 + threadIdx.x;
    const f32x4 v0 = *(const f32x4*)(E + (size_t)g * 8);
    const f32x4 v1 = *(const f32x4*)(E + (size_t)g * 8 + 4);
    unsigned int w0 = 0, w1 = 0;
    w0 = fp8x2_enc<false>(v0[0], v0[1], w0);
    w0 = fp8x2_enc<true >(v0[2], v0[3], w0);
    w1 = fp8x2_enc<false>(v1[0], v1[1], w1);
    w1 = fp8x2_enc<true >(v1[2], v1[3], w1);
    u32x2 o; o[0] = w0; o[1] = w1;
    *(u32x2*)(E8 + (size_t)g * 2) = o;
}

// ---------------- agg: dense wave-gather into wave-private LDS ---------------
// Per wave: 4 nodes x 16 rows (8 KB) staged with 8 dense global_load_lds
// (1 KB each), wave-local vmcnt(0) (no barrier: region is wave-private),
// then lane (g=lane>>4, c=lane&15) accumulates its own 8-byte column slice
// over the 16 k rows via ds_read_b64. No cross-lane ops at all.
__device__ __forceinline__ void agg_core(const unsigned char* __restrict__ T,
                                         const int* __restrict__ nbr,
                                         unsigned char* lds_wave,  // 8 KB
                                         int node_base,            // first of 4 nodes
                                         int lane, float* a /*[8]*/) {
    const int rsub = lane >> 3;          // row-within-8 for staging
    const int bcol = (lane & 7) * 16;    // 16B chunk within 128B row
    const int* nb = nbr + node_base * KNBR;
#pragma unroll
    for (int i = 0; i < 8; ++i) {
        int nl = nb[i * 8 + rsub];       // row r = i*8+rsub -> node g=r>>4, k=r&15
        gload_lds16(T + (size_t)nl * 128 + bcol, lds_wave + i * 1024);
    }
    asm volatile("s_waitcnt vmcnt(0)" ::: "memory");
    __builtin_amdgcn_sched_barrier(0);
    const int g = lane >> 4;             // node within wave
    const int c = lane & 15;             // 8B column slice
#pragma unroll
    for (int j = 0; j < 8; ++j) a[j] = 0.f;
#pragma unroll
    for (int k = 0; k < KNBR; ++k) {
        const u32x2 v = *(const u32x2*)(lds_wave + (g * 16 + k) * 128 + c * 8);
        f32x2 f;
        f = fp8x2_dec<false>(v[0]); a[0] += f[0]; a[1] += f[1];
        f = fp8x2_dec<true >(v[0]); a[2] += f[0]; a[3] += f[1];
        f = fp8x2_dec<false>(v[1]); a[4] += f[0]; a[5] += f[1];
        f = fp8x2_dec<true >(v[1]); a[6] += f[0]; a[7] += f[1];
    }
}

// K1: H1 = mean_k E8[nbr] ; fp8 -> fp8.  16 nodes per 256-thread block.
__global__ __launch_bounds__(256) void agg1_kernel(const unsigned char* __restrict__ E8,
                                                   const int* __restrict__ nbr,
                                                   unsigned char* __restrict__ H1f8) {
    __shared__ unsigned char SL[4][8192];
    const int t = threadIdx.x, wave = t >> 6, lane = t & 63;
    const int node_base = blockIdx.x * 16 + wave * 4;
    float a[8];
    agg_core(E8, nbr, SL[wave], node_base, lane, a);
    const int g = lane >> 4, c = lane & 15;
    unsigned int o0 = 0, o1 = 0;
    o0 = fp8x2_enc<false>(a[0] * 0.0625f, a[1] * 0.0625f, o0);
    o0 = fp8x2_enc<true >(a[2] * 0.0625f, a[3] * 0.0625f, o0);
    o1 = fp8x2_enc<false>(a[4] * 0.0625f, a[5] * 0.0625f, o1);
    o1 = fp8x2_enc<true >(a[6] * 0.0625f, a[7] * 0.0625f, o1);
    u32x2 o; o[0] = o0; o[1] = o1;
    *(u32x2*)(H1f8 + (size_t)(node_base + g) * 128 + c * 8) = o;
}

// K2: H2 = mean_k H1f8[nbr] ; fp8 -> bf16.
__global__ __launch_bounds__(256) void agg2_kernel(const unsigned char* __restrict__ H1f8,
                                                   const int* __restrict__ nbr,
                                                   unsigned short* __restrict__ H2b) {
    __shared__ unsigned char SL[4][8192];
    const int t = threadIdx.x, wave = t >> 6, lane = t & 63;
    const int node_base = blockIdx.x * 16 + wave * 4;
    float a[8];
    agg_core(H1f8, nbr, SL[wave], node_base, lane, a);
    const int g = lane >> 4, c = lane & 15;
    u16x8 o;
#pragma unroll
    for (int j = 0; j < 8; ++j) o[j] = f2bf(a[j] * 0.0625f);
    *(u16x8*)(H2b + (size_t)(node_base + g) * DIM + c * 8) = o;
}

// ---------------- K3: persistent double-buffered pair MLP + loss -------------
// grid = 512 blocks (2/CU), each loops over tiles t = bid, bid+512, ... (<=4).
// Per iter: vmcnt(0) [only prev stage outstanding] -> raw barrier -> MFMA(cur)
// -> pairs prefetch + stage(next into cur^1) -> epilogue -> lgkmcnt(0)+barrier
// -> loss accum (labels/b1/W2/B-frags all preloaded; no other in-loop vmem).
__global__ __launch_bounds__(256, 2) void pair_mlp_kernel(
    const int* __restrict__ pairs, const int* __restrict__ labels,
    const unsigned short* __restrict__ H2b, const unsigned short* __restrict__ W1t,
    const float* __restrict__ b1, const float* __restrict__ W2,
    const float* __restrict__ b2, float* __restrict__ out) {
    __shared__ unsigned short As[2][MBLK * 256];   // 2 x 32 KiB
    __shared__ float LP[4][MBLK][2];               // 2 KiB
    __shared__ float wred[4];

    const int tid  = threadIdx.x;
    const int wave = tid >> 6;
    const int lane = tid & 63;
    const int bid  = blockIdx.x;

    const int lq   = (lane & 31) * 16;   // byte within 512B LDS row
    const int lr   = lane >> 5;          // which of 2 rows per stage instr
    const int half = lq >> 8;            // 0: src endpoint, 1: dst endpoint
    const int lg   = lane >> 4;          // k-group
    const int ll   = lane & 15;          // row (A) / col (B) in fragment
    const int col0 = wave * 32 + ll;
    const int col1 = col0 + 16;
    const int myN  = (NT - bid + GRID_P - 1) / GRID_P;

    // ---- prologue: scalars, labels, B fragments, stage tile bid -> buf0 ----
    const float b1v0 = b1[col0], b1v1 = b1[col1];
    const float w2a0 = W2[col0 * 2], w2b0 = W2[col0 * 2 + 1];
    const float w2a1 = W2[col1 * 2], w2b1 = W2[col1 * 2 + 1];
    const float b20 = b2[0], b21 = b2[1];
    int lab[4] = {0, 0, 0, 0};
#pragma unroll
    for (int j = 0; j < 4; ++j) {
        int tt = bid + j * GRID_P;
        if (tt < NT && tid < MBLK) {
            int pm = tt * MBLK + tid;
            if (pm < NPAIRS) lab[j] = labels[pm];
        }
    }
    bf16x8 breg0[8], breg1[8];
#pragma unroll
    for (int ks = 0; ks < 8; ++ks) {
        const int kb = ks * 64 + lg * 16;
        breg0[ks] = *(const bf16x8*)((const char*)W1t + col0 * 512 + kb);
        breg1[ks] = *(const bf16x8*)((const char*)W1t + col1 * 512 + kb);
    }
#pragma unroll
    for (int i = 0; i < 8; ++i) {
        int m0 = wave * 16 + i * 2;
        int m  = m0 + lr;
        int b  = lq ^ ((m & 7) << 4);
        int pm = bid * MBLK + m; if (pm >= NPAIRS) pm = NPAIRS - 1;
        int node = pairs[pm * 2 + half];
        gload_lds16((const char*)H2b + (size_t)node * 256 + (b & 255),
                    (char*)&As[0][0] + m0 * 512);
    }

    float lacc = 0.f;
#pragma unroll
    for (int j = 0; j < 4; ++j) {
        const int t = bid + j * GRID_P;
        if (t >= NT) break;
        int tn = t + GRID_P; if (tn >= NT) tn = t;   // tail: restage (unconsumed)
        const int cur = j & 1;

        // prev stage (for this tile) is the ONLY outstanding vmem here
        asm volatile("s_waitcnt vmcnt(0)" ::: "memory");
        __builtin_amdgcn_sched_barrier(0);
        __builtin_amdgcn_s_barrier();
        __builtin_amdgcn_sched_barrier(0);

        // pairs prefetch for next tile (latency covered by MFMA phase)
        int nd[8];
#pragma unroll
        for (int i = 0; i < 8; ++i) {
            int m  = wave * 16 + i * 2 + lr;
            int pm = tn * MBLK + m; if (pm >= NPAIRS) pm = NPAIRS - 1;
            nd[i] = pairs[pm * 2 + half];
        }

        // MFMA over As[cur]: C[64][32] per wave, K=256 in 8 steps
        f32x4 acc[4][2];
        {
            f32x4 z = {0.f, 0.f, 0.f, 0.f};
#pragma unroll
            for (int i = 0; i < 4; ++i) { acc[i][0] = z; acc[i][1] = z; }
        }
#pragma unroll
        for (int ks = 0; ks < 8; ++ks) {
            const int kb = ks * 64 + lg * 16;
#pragma unroll
            for (int mf = 0; mf < 4; ++mf) {
                int row = mf * 16 + ll;
                bf16x8 af = *(const bf16x8*)((const char*)&As[cur][0] + row * 512 + (kb ^ ((row & 7) << 4)));
                acc[mf][0] = __builtin_amdgcn_mfma_f32_16x16x32_bf16(af, breg0[ks], acc[mf][0], 0, 0, 0);
                acc[mf][1] = __builtin_amdgcn_mfma_f32_16x16x32_bf16(af, breg1[ks], acc[mf][1], 0, 0, 0);
            }
        }

        // stage next tile into As[cur^1] (in flight until next iter's vmcnt)
#pragma unroll
        for (int i = 0; i < 8; ++i) {
            int m0 = wave * 16 + i * 2;
            int m  = m0 + lr;
            int b  = lq ^ ((m & 7) << 4);
            gload_lds16((const char*)H2b + (size_t)nd[i] * 256 + (b & 255),
                        (char*)&As[cur ^ 1][0] + m0 * 512);
        }

        // epilogue: +b1, ReLU, @W2 partials, 16-lane reduce -> LP
#pragma unroll
        for (int mf = 0; mf < 4; ++mf) {
            float p0[4], p1[4];
#pragma unroll
            for (int r = 0; r < 4; ++r) {
                float h0 = fmaxf(acc[mf][0][r] + b1v0, 0.f);
                float h1 = fmaxf(acc[mf][1][r] + b1v1, 0.f);
                p0[r] = h0 * w2a0 + h1 * w2a1;
                p1[r] = h0 * w2b0 + h1 * w2b1;
            }
#pragma unroll
            for (int s = 1; s < 16; s <<= 1) {
#pragma unroll
                for (int r = 0; r < 4; ++r) {
                    p0[r] += __shfl_xor(p0[r], s, 16);
                    p1[r] += __shfl_xor(p1[r], s, 16);
                }
            }
            if (ll == 0) {
                int rb = mf * 16 + lg * 4;
#pragma unroll
                for (int r = 0; r < 4; ++r) {
                    LP[wave][rb + r][0] = p0[r];
                    LP[wave][rb + r][1] = p1[r];
                }
            }
        }
        asm volatile("s_waitcnt lgkmcnt(0)" ::: "memory");
        __builtin_amdgcn_sched_barrier(0);
        __builtin_amdgcn_s_barrier();
        __builtin_amdgcn_sched_barrier(0);

        // loss for tile t
        if (tid < MBLK) {
            int pm = t * MBLK + tid;
            if (pm < NPAIRS) {
                float l0 = b20 + LP[0][tid][0] + LP[1][tid][0] + LP[2][tid][0] + LP[3][tid][0];
                float l1 = b21 + LP[0][tid][1] + LP[1][tid][1] + LP[2][tid][1] + LP[3][tid][1];
                float mx = fmaxf(l0, l1);
                float e0 = __expf(l0 - mx), e1 = __expf(l1 - mx);
                float inv = 1.f / (e0 + e1);
                float q0 = e0 * inv, q1 = e1 * inv;
                float lse2 = __logf(__expf(q0) + __expf(q1));
                lacc += lse2 - (lab[j] ? q1 : q0);
            }
        }
    }

    __syncthreads();   // drains dangling tail stage; safe outside the loop
#pragma unroll
    for (int s = 1; s < 64; s <<= 1) lacc += __shfl_xor(lacc, s, 64);
    if (lane == 0) wred[wave] = lacc;
    __syncthreads();
    if (tid == 0)
        atomicAdd(out, (wred[0] + wred[1] + wred[2] + wred[3]) * (1.0f / (float)NPAIRS));
}

extern "C" void kernel_launch(void* const* d_in, const int* in_sizes, int n_in,
                              void* d_out, int out_size, void* d_ws, size_t ws_size,
                              hipStream_t stream) {
    const int*   pairs  = (const int*)d_in[0];
    const int*   labels = (const int*)d_in[1];
    const int*   nbr    = (const int*)d_in[2];
    const float* E      = (const float*)d_in[3];
    const float* W1     = (const float*)d_in[4];
    const float* b1     = (const float*)d_in[5];
    const float* W2     = (const float*)d_in[6];
    const float* b2     = (const float*)d_in[7];
    float* out = (float*)d_out;

    // workspace: W1t bf16 (64KB) | E8 fp8 (6.4MB) | H1f8 fp8 (6.4MB) | H2b bf16 (12.8MB)
    char* ws = (char*)d_ws;
    unsigned short* W1t  = (unsigned short*)(ws);
    unsigned char*  E8   = (unsigned char*)(ws + 65536);
    unsigned char*  H1f8 = E8 + (size_t)NNODES * DIM;
    unsigned short* H2b  = (unsigned short*)(H1f8 + (size_t)NNODES * DIM);

    (void)hipMemsetAsync(out, 0, sizeof(float), stream);

    w1t_kernel<<<dim3(128), dim3(256), 0, stream>>>(W1, W1t);
    e2f8_kernel<<<dim3((NNODES * DIM) / (256 * 8)), dim3(256), 0, stream>>>(E, (unsigned int*)E8);
    agg1_kernel<<<dim3(NNODES / 16), dim3(256), 0, stream>>>(E8, nbr, H1f8);
    agg2_kernel<<<dim3(NNODES / 16), dim3(256), 0, stream>>>(H1f8, nbr, H2b);
    pair_mlp_kernel<<<dim3(GRID_P), dim3(256), 0, stream>>>(
        pairs, labels, H2b, W1t, b1, W2, b2, out);
}